// Round 1
// baseline (87.297 us; speedup 1.0000x reference)
//
#include <hip/hip_runtime.h>

// Problem constants (fixed by the reference)
#define S_N 32
#define O_N 64
#define A_N 8
#define R_N 8
#define B_N 1024
#define T_N 128

// Workspace layout (in floats)
//  [0, 8192)          pk  : packed transposed transitions
//                      pk[((a*8+cc)*32 + r)*4 + j] = Tr[s=cc*4+j][a][r]
//                      where Tr[s][a][s'] = softmax_{s'}(params_s_sa[s][a][:])
//  [8192, 8192+2592)  tab : OT[64*32] | RT[8*32] | AT[8*32] | pi[32]
#define PK_OFF   0
#define TAB_OFF  8192
#define OT_OFF   0
#define RT_OFF   2048
#define AT_OFF   2304
#define PI_OFF   2560
#define TAB_N    2592

__global__ __launch_bounds__(384) void tam_prep(
    const float* __restrict__ params_s,
    const float* __restrict__ params_s_sa,
    const float* __restrict__ params_o_s,
    const float* __restrict__ params_r_s,
    const float* __restrict__ params_a_s,
    float* __restrict__ ws)
{
    const int tid = threadIdx.x;
    float* pk  = ws + PK_OFF;
    float* tab = ws + TAB_OFF;

    if (tid < 256) {
        // One (s, a) transition row each: softmax over s' (32 values)
        const int s = tid >> 3, a = tid & 7;
        const float* row = params_s_sa + (s * A_N + a) * S_N;
        float mx = row[0];
        #pragma unroll 1
        for (int i = 1; i < S_N; ++i) mx = fmaxf(mx, row[i]);
        float sum = 0.f;
        #pragma unroll 1
        for (int i = 0; i < S_N; ++i) sum += __expf(row[i] - mx);
        const float inv = 1.0f / sum;
        const int cc = s >> 2, j = s & 3;
        #pragma unroll 1
        for (int r = 0; r < S_N; ++r)
            pk[(size_t)((a * 8 + cc) * 32 + r) * 4 + j] = __expf(row[r] - mx) * inv;
    } else if (tid < 288) {
        // Observation emission: softmax over O (64) per state s; store transposed OT[o][s]
        const int s = tid - 256;
        const float* row = params_o_s + s * O_N;
        float mx = row[0];
        #pragma unroll 1
        for (int i = 1; i < O_N; ++i) mx = fmaxf(mx, row[i]);
        float sum = 0.f;
        #pragma unroll 1
        for (int i = 0; i < O_N; ++i) sum += __expf(row[i] - mx);
        const float inv = 1.0f / sum;
        #pragma unroll 1
        for (int o = 0; o < O_N; ++o) tab[OT_OFF + o * 32 + s] = __expf(row[o] - mx) * inv;
    } else if (tid < 320) {
        // Reward emission: softmax over R (8) per state s; RT[r][s]
        const int s = tid - 288;
        const float* row = params_r_s + s * R_N;
        float mx = row[0];
        #pragma unroll 1
        for (int i = 1; i < R_N; ++i) mx = fmaxf(mx, row[i]);
        float sum = 0.f;
        #pragma unroll 1
        for (int i = 0; i < R_N; ++i) sum += __expf(row[i] - mx);
        const float inv = 1.0f / sum;
        #pragma unroll 1
        for (int r = 0; r < R_N; ++r) tab[RT_OFF + r * 32 + s] = __expf(row[r] - mx) * inv;
    } else if (tid < 352) {
        // Action prior: softmax over A (8) per state s; AT[a][s]
        const int s = tid - 320;
        const float* row = params_a_s + s * A_N;
        float mx = row[0];
        #pragma unroll 1
        for (int i = 1; i < A_N; ++i) mx = fmaxf(mx, row[i]);
        float sum = 0.f;
        #pragma unroll 1
        for (int i = 0; i < A_N; ++i) sum += __expf(row[i] - mx);
        const float inv = 1.0f / sum;
        #pragma unroll 1
        for (int a = 0; a < A_N; ++a) tab[AT_OFF + a * 32 + s] = __expf(row[a] - mx) * inv;
    } else if (tid == 352) {
        // Initial state distribution pi = softmax(params_s)
        float mx = params_s[0];
        #pragma unroll 1
        for (int i = 1; i < S_N; ++i) mx = fmaxf(mx, params_s[i]);
        float sum = 0.f;
        #pragma unroll 1
        for (int i = 0; i < S_N; ++i) sum += __expf(params_s[i] - mx);
        const float inv = 1.0f / sum;
        #pragma unroll 1
        for (int i = 0; i < S_N; ++i) tab[PI_OFF + i] = __expf(params_s[i] - mx) * inv;
    }
}

#define RLI(v, l) __builtin_amdgcn_readlane((v), (l))
#define RLF(v, l) __int_as_float(__builtin_amdgcn_readlane(__float_as_int(v), (l)))

// One wave (64 lanes) per episode. lane&31 = destination state s'; both
// 32-lane halves hold identical replicated data -> fully uniform control flow.
// tr[8][32] (all 8 actions' transition columns for this lane's s') lives in
// VGPRs; matvec = 32 x { readlane(w,s) -> SGPR, v_fmac with SGPR operand }.
__global__ __launch_bounds__(64, 1) void tam_main(
    const float* __restrict__ regime,
    const int*   __restrict__ obs,
    const int*   __restrict__ rewards,
    const int*   __restrict__ dones_i,   // float32 0/1 read as int bits
    const int*   __restrict__ actions,
    const float* __restrict__ ws,
    float* __restrict__ out)
{
    __shared__ float sTab[TAB_N];
    const int lane = threadIdx.x;
    const int sl   = lane & 31;
    const int b    = blockIdx.x;

    // Stage small emission tables into LDS (contiguous copy, coalesced)
    {
        const float4* g4 = reinterpret_cast<const float4*>(ws + TAB_OFF);
        float4* s4 = reinterpret_cast<float4*>(sTab);
        #pragma unroll 1
        for (int i = lane; i < TAB_N / 4; i += 64) s4[i] = g4[i];
    }
    __syncthreads();

    // Load all 8 transition matrices' columns for state sl into VGPRs.
    // pk layout makes these loads lane-consecutive (coalesced / broadcast).
    float tr[8][32];
    {
        const float4* pk4 = reinterpret_cast<const float4*>(ws + PK_OFF);
        #pragma unroll
        for (int a = 0; a < 8; ++a) {
            #pragma unroll
            for (int cc = 0; cc < 8; ++cc) {
                float4 v = pk4[(a * 8 + cc) * 32 + sl];
                tr[a][cc * 4 + 0] = v.x; tr[a][cc * 4 + 1] = v.y;
                tr[a][cc * 4 + 2] = v.z; tr[a][cc * 4 + 3] = v.w;
            }
        }
    }

    // Bulk-load per-step scalars: lane t holds step t's index (extracted
    // per step with readlane -> no per-step global-load latency).
    const int vo0 = obs[lane * B_N + b];
    const int vo1 = obs[(64 + lane) * B_N + b];
    const int oF  = obs[128 * B_N + b];
    const int vr0 = rewards[lane * B_N + b];
    const int vr1 = rewards[(64 + lane) * B_N + b];
    const int rF  = rewards[128 * B_N + b];
    const int vd0 = dones_i[lane * B_N + b];
    const int vd1 = dones_i[(64 + lane) * B_N + b];
    const int va0 = actions[lane * B_N + b];
    const int va1 = actions[(64 + lane) * B_N + b];
    const bool skipA = (regime[b] == 1.0f);

    const float* sOT = sTab + OT_OFF;
    const float* sRT = sTab + RT_OFF;
    const float* sAT = sTab + AT_OFF;

    float u = sTab[PI_OFF + sl];   // unnormalized belief (linear space)
    float accLog = 0.0f;           // accumulated log of pulled-out scales
    float result = 0.0f;
    bool finished = false;

    #pragma unroll 1
    for (int ph = 0; ph < 2; ++ph) {
        if (finished) break;
        const int vo = ph ? vo1 : vo0;
        const int vr = ph ? vr1 : vr0;
        const int vd = ph ? vd1 : vd0;
        const int va = ph ? va1 : va0;
        #pragma unroll 1
        for (int tt = 0; tt < 64; ++tt) {
            const int o = RLI(vo, tt);
            const int r = RLI(vr, tt);
            const int d = RLI(vd, tt);
            const int a = RLI(va, tt);
            const bool dnow = (d != 0);                 // dones are exactly 0.0f/1.0f
            float e = sOT[o * 32 + sl] * sRT[r * 32 + sl];
            const float av = sAT[a * 32 + sl];
            if (!dnow && !skipA) e *= av;               // A-term excluded if done|regime
            const float w = u * e;

            if (dnow) {
                // First done step: contributes with A excluded, then episode freezes.
                float t = w;
                t += __shfl_xor(t, 1, 32);
                t += __shfl_xor(t, 2, 32);
                t += __shfl_xor(t, 4, 32);
                t += __shfl_xor(t, 8, 32);
                t += __shfl_xor(t, 16, 32);
                result = accLog + __logf(t);
                finished = true;
                break;
            }

            // u_next[s'] = sum_s w[s] * Tr[s][a][s']   (tr[a][s] = Tr[s][a][sl])
            float acc0 = 0.f, acc1 = 0.f, acc2 = 0.f, acc3 = 0.f;
            #define MVROW(A_, s4_) \
                acc0 = fmaf(RLF(w, 4*(s4_)+0), tr[A_][4*(s4_)+0], acc0); \
                acc1 = fmaf(RLF(w, 4*(s4_)+1), tr[A_][4*(s4_)+1], acc1); \
                acc2 = fmaf(RLF(w, 4*(s4_)+2), tr[A_][4*(s4_)+2], acc2); \
                acc3 = fmaf(RLF(w, 4*(s4_)+3), tr[A_][4*(s4_)+3], acc3);
            #define MV(A_) { MVROW(A_,0) MVROW(A_,1) MVROW(A_,2) MVROW(A_,3) \
                             MVROW(A_,4) MVROW(A_,5) MVROW(A_,6) MVROW(A_,7) }
            switch (a) {                                 // wave-uniform branch
                case 0: MV(0); break;
                case 1: MV(1); break;
                case 2: MV(2); break;
                case 3: MV(3); break;
                case 4: MV(4); break;
                case 5: MV(5); break;
                case 6: MV(6); break;
                default: MV(7); break;
            }
            u = (acc0 + acc1) + (acc2 + acc3);

            // Exact power-of-two rescale every 4 steps (keeps u in fp32 range;
            // u's component spread is bounded by Tr's spread, so a 4-sample
            // proxy of the magnitude is safe).
            if ((tt & 3) == 3) {
                const float m = (RLF(u, 0) + RLF(u, 8)) + (RLF(u, 16) + RLF(u, 24));
                const int k = (__float_as_int(m) >> 23) & 255;   // biased exponent
                const float scale = __int_as_float((254 - k) << 23);  // 2^(127-k)
                u *= scale;
                accLog += (float)(k - 127) * 0.69314718055994531f;
            }
        }
    }

    if (!finished) {
        // Final step t = T: emissions only, no action term, no transition.
        float w = u * sOT[oF * 32 + sl] * sRT[rF * 32 + sl];
        float t = w;
        t += __shfl_xor(t, 1, 32);
        t += __shfl_xor(t, 2, 32);
        t += __shfl_xor(t, 4, 32);
        t += __shfl_xor(t, 8, 32);
        t += __shfl_xor(t, 16, 32);
        result = accLog + __logf(t);
    }

    if (lane == 0) out[b] = result;
}

extern "C" void kernel_launch(void* const* d_in, const int* in_sizes, int n_in,
                              void* d_out, int out_size, void* d_ws, size_t ws_size,
                              hipStream_t stream) {
    (void)in_sizes; (void)n_in; (void)out_size; (void)ws_size;
    const float* regime      = (const float*)d_in[0];
    const int*   obs         = (const int*)d_in[1];
    const int*   rewards     = (const int*)d_in[2];
    const int*   dones_i     = (const int*)d_in[3];
    const int*   actions     = (const int*)d_in[4];
    const float* params_s    = (const float*)d_in[5];
    const float* params_s_sa = (const float*)d_in[6];
    const float* params_o_s  = (const float*)d_in[7];
    const float* params_r_s  = (const float*)d_in[8];
    const float* params_a_s  = (const float*)d_in[9];
    float* ws  = (float*)d_ws;
    float* out = (float*)d_out;

    tam_prep<<<1, 384, 0, stream>>>(params_s, params_s_sa, params_o_s,
                                    params_r_s, params_a_s, ws);
    tam_main<<<1024, 64, 0, stream>>>(regime, obs, rewards, dones_i, actions, ws, out);
}

// Round 3
// 48.166 us; speedup vs baseline: 1.8124x; 1.8124x over previous
//
#include <hip/hip_runtime.h>

// Problem constants (fixed by the reference)
#define S_N 32
#define O_N 64
#define A_N 8
#define R_N 8
#define B_N 1024
#define T_N 128

// Workspace layout (float index offsets)
//  TP : float2-packed transitions Tp[a][s2][sl] = (Tr[2*s2][a][sl], Tr[2*s2+1][a][sl])
//       where Tr[s][a][s'] = softmax_{s'}(params_s_sa[s][a][:])   -> 8192 floats
//  OT : OT[o][s] = P(o|s)                                          -> 2048 floats
//  RA : RA[r*8+a][s] = P(r|s)*P(a|s)                               -> 2048 floats
//  RT : RT[r][s] = P(r|s)                                          -> 256 floats
//  PI : pi[s]                                                      -> 32 floats
#define TP_OFF   0
#define OT_OFF   8192
#define RA_OFF   10240
#define RT_OFF   12288
#define PI_OFF   12544

__global__ __launch_bounds__(512) void tam_prep(
    const float* __restrict__ params_s,
    const float* __restrict__ params_s_sa,
    const float* __restrict__ params_o_s,
    const float* __restrict__ params_r_s,
    const float* __restrict__ params_a_s,
    float* __restrict__ ws)
{
    __shared__ float sRT[256], sAT[256];
    const int tid = threadIdx.x;

    if (tid < 256) {
        // one (s,a) transition row each: softmax over s' (32 values)
        const int s = tid >> 3, a = tid & 7;
        const float* row = params_s_sa + (s * A_N + a) * S_N;
        float p[32];
        #pragma unroll
        for (int i = 0; i < 8; ++i) {
            float4 v = reinterpret_cast<const float4*>(row)[i];
            p[4*i] = v.x; p[4*i+1] = v.y; p[4*i+2] = v.z; p[4*i+3] = v.w;
        }
        float mx = p[0];
        #pragma unroll
        for (int i = 1; i < 32; ++i) mx = fmaxf(mx, p[i]);
        float sum = 0.f;
        #pragma unroll
        for (int i = 0; i < 32; ++i) { p[i] = __expf(p[i] - mx); sum += p[i]; }
        const float inv = 1.0f / sum;
        // scatter into float2-packed layout: float index ((a*16+s2)*32+sl)*2 + (s&1)
        float* base = ws + TP_OFF + (size_t)((a * 16 + (s >> 1)) * 32) * 2 + (s & 1);
        #pragma unroll
        for (int sl = 0; sl < 32; ++sl) base[sl * 2] = p[sl] * inv;
    } else if (tid < 288) {
        // observation emission: softmax over O (64) per state; store transposed OT[o][s]
        const int s = tid - 256;
        const float* row = params_o_s + s * O_N;
        float p[64];
        #pragma unroll
        for (int i = 0; i < 16; ++i) {
            float4 v = reinterpret_cast<const float4*>(row)[i];
            p[4*i] = v.x; p[4*i+1] = v.y; p[4*i+2] = v.z; p[4*i+3] = v.w;
        }
        float mx = p[0];
        #pragma unroll
        for (int i = 1; i < 64; ++i) mx = fmaxf(mx, p[i]);
        float sum = 0.f;
        #pragma unroll
        for (int i = 0; i < 64; ++i) { p[i] = __expf(p[i] - mx); sum += p[i]; }
        const float inv = 1.0f / sum;
        #pragma unroll
        for (int o = 0; o < 64; ++o) ws[OT_OFF + o * 32 + s] = p[o] * inv;
    } else if (tid < 320) {
        // reward emission: softmax over R (8) per state; RT[r][s]
        const int s = tid - 288;
        const float* row = params_r_s + s * R_N;
        float p[8];
        #pragma unroll
        for (int i = 0; i < 2; ++i) {
            float4 v = reinterpret_cast<const float4*>(row)[i];
            p[4*i] = v.x; p[4*i+1] = v.y; p[4*i+2] = v.z; p[4*i+3] = v.w;
        }
        float mx = p[0];
        #pragma unroll
        for (int i = 1; i < 8; ++i) mx = fmaxf(mx, p[i]);
        float sum = 0.f;
        #pragma unroll
        for (int i = 0; i < 8; ++i) { p[i] = __expf(p[i] - mx); sum += p[i]; }
        const float inv = 1.0f / sum;
        #pragma unroll
        for (int r = 0; r < 8; ++r) {
            const float v = p[r] * inv;
            ws[RT_OFF + r * 32 + s] = v;
            sRT[r * 32 + s] = v;
        }
    } else if (tid < 352) {
        // action prior: softmax over A (8) per state; AT[a][s] (LDS only, feeds RA)
        const int s = tid - 320;
        const float* row = params_a_s + s * A_N;
        float p[8];
        #pragma unroll
        for (int i = 0; i < 2; ++i) {
            float4 v = reinterpret_cast<const float4*>(row)[i];
            p[4*i] = v.x; p[4*i+1] = v.y; p[4*i+2] = v.z; p[4*i+3] = v.w;
        }
        float mx = p[0];
        #pragma unroll
        for (int i = 1; i < 8; ++i) mx = fmaxf(mx, p[i]);
        float sum = 0.f;
        #pragma unroll
        for (int i = 0; i < 8; ++i) { p[i] = __expf(p[i] - mx); sum += p[i]; }
        const float inv = 1.0f / sum;
        #pragma unroll
        for (int a = 0; a < 8; ++a) sAT[a * 32 + s] = p[a] * inv;
    } else if (tid < 384) {
        // pi = softmax(params_s): 32 threads compute redundantly, write own element
        const int s = tid - 352;
        float p[32];
        #pragma unroll
        for (int i = 0; i < 8; ++i) {
            float4 v = reinterpret_cast<const float4*>(params_s)[i];
            p[4*i] = v.x; p[4*i+1] = v.y; p[4*i+2] = v.z; p[4*i+3] = v.w;
        }
        float mx = p[0];
        #pragma unroll
        for (int i = 1; i < 32; ++i) mx = fmaxf(mx, p[i]);
        float sum = 0.f;
        #pragma unroll
        for (int i = 0; i < 32; ++i) { p[i] = __expf(p[i] - mx); sum += p[i]; }
        ws[PI_OFF + s] = p[s] / sum;
    }
    __syncthreads();
    // RA[r*8+a][s] = RT[r][s] * AT[a][s]
    #pragma unroll 1
    for (int i = tid; i < 2048; i += 512) {
        const int sl = i & 31, ra = i >> 5;
        ws[RA_OFF + i] = sRT[(ra >> 3) * 32 + sl] * sAT[(ra & 7) * 32 + sl];
    }
}

#define RLI(v, l) __builtin_amdgcn_readlane((v), (l))
#define RLF(v, l) __int_as_float(__builtin_amdgcn_readlane(__float_as_int(v), (l)))

// Load the 16 float2 T-row-pairs for action A_ into P[0..15] (constant indices
// only -> stays in registers, rule #20)
#define LOADT(P, A_) {                                                   \
    const int tb_ = (A_) * 512 + sl;                                     \
    P[0]  = sT[tb_ +  0*32]; P[1]  = sT[tb_ +  1*32];                    \
    P[2]  = sT[tb_ +  2*32]; P[3]  = sT[tb_ +  3*32];                    \
    P[4]  = sT[tb_ +  4*32]; P[5]  = sT[tb_ +  5*32];                    \
    P[6]  = sT[tb_ +  6*32]; P[7]  = sT[tb_ +  7*32];                    \
    P[8]  = sT[tb_ +  8*32]; P[9]  = sT[tb_ +  9*32];                    \
    P[10] = sT[tb_ + 10*32]; P[11] = sT[tb_ + 11*32];                    \
    P[12] = sT[tb_ + 12*32]; P[13] = sT[tb_ + 13*32];                    \
    P[14] = sT[tb_ + 14*32]; P[15] = sT[tb_ + 15*32]; }

// Load emission factors for the step encoded in low 16 bits of PKW
#define LOADE(EO, ERA, PKW) {                                            \
    const unsigned pk_ = (PKW);                                          \
    EO  = ws[OT_OFF + (int)(pk_ & 63u) * 32 + sl];                       \
    ERA = ws[eBase + (int)((pk_ >> 6) & 7u) * eMulR                      \
                   + (int)((pk_ >> 9) & 7u) * eMulA + sl]; }

// One HMM step: w = u .* e ; u' = T_a^T w  (32 SGPR broadcasts + 32 fmacs)
#define STEP_COMPUTE(EO, ERA, TT) {                                      \
    const float wv = u * (EO) * (ERA);                                   \
    const float w0 =RLF(wv,0),  w1 =RLF(wv,1),  w2 =RLF(wv,2),  w3 =RLF(wv,3),  \
                w4 =RLF(wv,4),  w5 =RLF(wv,5),  w6 =RLF(wv,6),  w7 =RLF(wv,7),  \
                w8 =RLF(wv,8),  w9 =RLF(wv,9),  w10=RLF(wv,10), w11=RLF(wv,11), \
                w12=RLF(wv,12), w13=RLF(wv,13), w14=RLF(wv,14), w15=RLF(wv,15), \
                w16=RLF(wv,16), w17=RLF(wv,17), w18=RLF(wv,18), w19=RLF(wv,19), \
                w20=RLF(wv,20), w21=RLF(wv,21), w22=RLF(wv,22), w23=RLF(wv,23), \
                w24=RLF(wv,24), w25=RLF(wv,25), w26=RLF(wv,26), w27=RLF(wv,27), \
                w28=RLF(wv,28), w29=RLF(wv,29), w30=RLF(wv,30), w31=RLF(wv,31); \
    float c0 = 0.f, c1 = 0.f, c2 = 0.f, c3 = 0.f;                        \
    c0 = fmaf(w0,  TT[0].x,  c0); c1 = fmaf(w1,  TT[0].y,  c1);          \
    c2 = fmaf(w2,  TT[1].x,  c2); c3 = fmaf(w3,  TT[1].y,  c3);          \
    c0 = fmaf(w4,  TT[2].x,  c0); c1 = fmaf(w5,  TT[2].y,  c1);          \
    c2 = fmaf(w6,  TT[3].x,  c2); c3 = fmaf(w7,  TT[3].y,  c3);          \
    c0 = fmaf(w8,  TT[4].x,  c0); c1 = fmaf(w9,  TT[4].y,  c1);          \
    c2 = fmaf(w10, TT[5].x,  c2); c3 = fmaf(w11, TT[5].y,  c3);          \
    c0 = fmaf(w12, TT[6].x,  c0); c1 = fmaf(w13, TT[6].y,  c1);          \
    c2 = fmaf(w14, TT[7].x,  c2); c3 = fmaf(w15, TT[7].y,  c3);          \
    c0 = fmaf(w16, TT[8].x,  c0); c1 = fmaf(w17, TT[8].y,  c1);          \
    c2 = fmaf(w18, TT[9].x,  c2); c3 = fmaf(w19, TT[9].y,  c3);          \
    c0 = fmaf(w20, TT[10].x, c0); c1 = fmaf(w21, TT[10].y, c1);          \
    c2 = fmaf(w22, TT[11].x, c2); c3 = fmaf(w23, TT[11].y, c3);          \
    c0 = fmaf(w24, TT[12].x, c0); c1 = fmaf(w25, TT[12].y, c1);          \
    c2 = fmaf(w26, TT[13].x, c2); c3 = fmaf(w27, TT[13].y, c3);          \
    c0 = fmaf(w28, TT[14].x, c0); c1 = fmaf(w29, TT[14].y, c1);          \
    c2 = fmaf(w30, TT[15].x, c2); c3 = fmaf(w31, TT[15].y, c3);          \
    u = (c0 + c1) + (c2 + c3); }

// One wave (64 lanes) per episode. lane&31 = destination state s' (halves
// replicated for the belief vector). T in LDS (float2 pairs), emissions from
// global (L1-resident), everything prefetched one step ahead.
__global__ __launch_bounds__(64, 1) void tam_main(
    const float* __restrict__ regime,
    const int*   __restrict__ obs,
    const int*   __restrict__ rewards,
    const int*   __restrict__ dones_i,   // float32 0/1 read as int bits
    const int*   __restrict__ actions,
    const float* __restrict__ ws,
    float* __restrict__ out)
{
    __shared__ float2 sT[8 * 16 * 32];   // 32 KB
    const int lane = threadIdx.x;
    const int sl   = lane & 31;
    const int b    = blockIdx.x;

    // stage packed T into LDS (single wave -> no barrier anywhere)
    {
        const float4* g4 = reinterpret_cast<const float4*>(ws + TP_OFF);
        float4* s4 = reinterpret_cast<float4*>(sT);
        #pragma unroll
        for (int i = 0; i < 32; ++i) s4[lane + i * 64] = g4[lane + i * 64];
    }

    // per-lane packed step-pair indices: lane i holds steps 2i (low16), 2i+1 (high16)
    const int t0 = 2 * lane, t1 = 2 * lane + 1;
    const int o0 = obs[t0 * B_N + b],      o1 = obs[t1 * B_N + b];
    const int r0 = rewards[t0 * B_N + b],  r1 = rewards[t1 * B_N + b];
    const int a0 = actions[t0 * B_N + b],  a1 = actions[t1 * B_N + b];
    const int d0 = dones_i[t0 * B_N + b],  d1 = dones_i[t1 * B_N + b];
    const int vpk = (o0 | (r0 << 6) | (a0 << 9)) |
                    ((o1 | (r1 << 6) | (a1 << 9)) << 16);

    // first-done step t* via ballot (no done checks in the hot loop)
    const unsigned long long mE = __ballot(d0 != 0);
    const unsigned long long mO = __ballot(d1 != 0);
    const int tE = mE ? 2 * __builtin_ctzll(mE)     : (1 << 30);
    const int tO = mO ? 2 * __builtin_ctzll(mO) + 1 : (1 << 30);
    const int tstar  = tE < tO ? tE : tO;
    const int nsteps = tstar < 128 ? tstar : 128;

    // regime==1 -> action term excluded every step: use RT table (a ignored)
    const bool skipA = (regime[b] == 1.0f);
    const int eBase = skipA ? RT_OFF : RA_OFF;
    const int eMulR = skipA ? 32 : 256;
    const int eMulA = skipA ? 0 : 32;

    float u = ws[PI_OFF + sl];
    int ksum = 0;

    float2 TA[16], TB[16];
    float eoA, eraA, eoB, eraB;

    unsigned pkc = (unsigned)RLI(vpk, 0);
    unsigned pkn = (unsigned)RLI(vpk, 1);
    LOADE(eoA, eraA, pkc & 0xffffu);
    LOADT(TA, (int)((pkc >> 9) & 7u));

    const int npairs = nsteps >> 1;
    #pragma unroll 1
    for (int i = 0; i < npairs; ++i) {
        // prefetch step 2i+1 (B)
        const unsigned pkB = pkc >> 16;
        LOADE(eoB, eraB, pkB);
        LOADT(TB, (int)((pkB >> 9) & 7u));
        // compute step 2i (A)
        STEP_COMPUTE(eoA, eraA, TA);
        // prefetch step 2i+2 (next A)
        LOADE(eoA, eraA, pkn & 0xffffu);
        LOADT(TA, (int)((pkn >> 9) & 7u));
        // compute step 2i+1 (B)
        STEP_COMPUTE(eoB, eraB, TB);
        // rotate packed indices (readlane of lane>=64 wraps mod 64: fields
        // are always in-range, result unused past the end)
        pkc = pkn;
        pkn = (unsigned)RLI(vpk, i + 2);
        // exact power-of-two rescale every 2 steps (SALU exponent math)
        const int ub = RLI(__float_as_int(u), 0);
        const int kb = (ub >> 23) & 255;
        u *= __int_as_float((254 - kb) << 23);
        ksum += kb - 127;
    }

    if (nsteps & 1) {           // leftover even-index step (data already staged)
        STEP_COMPUTE(eoA, eraA, TA);
    }

    // terminal contribution at e = min(t*, 128): OT*RT only (no action term)
    {
        const int e  = nsteps;
        const int oe = obs[e * B_N + b];
        const int re = rewards[e * B_N + b];
        const float eo = ws[OT_OFF + oe * 32 + sl];
        const float rt = ws[RT_OFF + re * 32 + sl];
        float t = u * eo * rt;
        t += __shfl_xor(t, 1, 32);
        t += __shfl_xor(t, 2, 32);
        t += __shfl_xor(t, 4, 32);
        t += __shfl_xor(t, 8, 32);
        t += __shfl_xor(t, 16, 32);
        const float result = (float)ksum * 0.69314718055994531f + __logf(t);
        if (lane == 0) out[b] = result;
    }
}

extern "C" void kernel_launch(void* const* d_in, const int* in_sizes, int n_in,
                              void* d_out, int out_size, void* d_ws, size_t ws_size,
                              hipStream_t stream) {
    (void)in_sizes; (void)n_in; (void)out_size; (void)ws_size;
    const float* regime      = (const float*)d_in[0];
    const int*   obs         = (const int*)d_in[1];
    const int*   rewards     = (const int*)d_in[2];
    const int*   dones_i     = (const int*)d_in[3];
    const int*   actions     = (const int*)d_in[4];
    const float* params_s    = (const float*)d_in[5];
    const float* params_s_sa = (const float*)d_in[6];
    const float* params_o_s  = (const float*)d_in[7];
    const float* params_r_s  = (const float*)d_in[8];
    const float* params_a_s  = (const float*)d_in[9];
    float* ws  = (float*)d_ws;
    float* out = (float*)d_out;

    tam_prep<<<1, 512, 0, stream>>>(params_s, params_s_sa, params_o_s,
                                    params_r_s, params_a_s, ws);
    tam_main<<<1024, 64, 0, stream>>>(regime, obs, rewards, dones_i, actions, ws, out);
}